// Round 4
// baseline (585.282 us; speedup 1.0000x reference)
//
#include <hip/hip_runtime.h>

typedef unsigned int  u32;
typedef unsigned short u16;
typedef __attribute__((ext_vector_type(8))) short short8;
typedef __attribute__((ext_vector_type(4))) float f32x4;

#define CI 64
#define CO 128
#define HH 128
#define WW 128
#define HO 126
#define WO 126

// round-to-nearest-even fp32 -> bf16 (bits)
__device__ __forceinline__ u16 f2bf(float f) {
    u32 u = __builtin_bit_cast(u32, f);
    u = (u + 0x7FFFu + ((u >> 16) & 1u)) >> 16;
    return (u16)u;
}

// ---- kernel 1: reorder weights (C_out,C_in,3,3) fp32 -> [tap][co][ci] bf16 ----
// persistent-ish: 72 blocks x 1024 elems
__global__ void reorder_w(const float* __restrict__ w, u16* __restrict__ wq) {
    int base = blockIdx.x * 1024 + threadIdx.x;
#pragma unroll
    for (int t = 0; t < 4; ++t) {
        int i   = base + t * 256;               // covers 73728 exactly
        int ci  = i & 63;
        int co  = (i >> 6) & 127;
        int tap = i >> 13;
        wq[i] = f2bf(w[(co * CI + ci) * 9 + tap]);
    }
}

// ---- kernel 2 (fast path): x fp32 NCHW -> bf16 swizzled-NHWC in ws ----
// persistent: 512 blocks x 8 rows. Coalesced reads + LDS transpose.
// Global layout out: xq[(n*128+h)*8192 + w*64 + slot*8 + j], ci = (slot^(w&7))*8 + j.
__global__ __launch_bounds__(256)
void prep_x(const float* __restrict__ x, u16* __restrict__ xq) {
    __shared__ float lf[64 * 128];         // 32 KB
    const int w4  = threadIdx.x & 31;      // float4 index along w
    const int ci0 = threadIdx.x >> 5;      // 0..7

    for (int t = 0; t < 8; ++t) {
        const int row = blockIdx.x * 8 + t; // n*128 + h, 4096 rows
        const int n = row >> 7, h = row & 127;
        const float* xb = x + (size_t)n * CI * HH * WW + (size_t)h * WW;

#pragma unroll
        for (int it = 0; it < 8; ++it) {
            int ci = it * 8 + ci0;
            f32x4 v = *(const f32x4*)(xb + (size_t)ci * (HH * WW) + w4 * 4);  // coalesced
            int s = (ci >> 3) ^ (ci & 7);
            *(f32x4*)&lf[ci * 128 + ((w4 ^ s) * 4)] = v;
        }
        __syncthreads();

        u16* dst = xq + (size_t)row * 8192;
#pragma unroll
        for (int it = 0; it < 4; ++it) {
            int idx  = it * 256 + threadIdx.x; // 1024 = 128 w * 8 slots
            int slot = idx & 7;
            int w    = idx >> 3;
            int g    = slot ^ (w & 7);
            int wq4  = w >> 2, wr = w & 3;
            u32 parts[4];
#pragma unroll
            for (int jj = 0; jj < 4; ++jj) {
                int ca = g * 8 + 2 * jj;
                int cb = ca + 1;
                float va = lf[ca * 128 + ((wq4 ^ ((ca >> 3) ^ (ca & 7))) * 4) + wr];
                float vb = lf[cb * 128 + ((wq4 ^ ((cb >> 3) ^ (cb & 7))) * 4) + wr];
                parts[jj] = (u32)f2bf(va) | ((u32)f2bf(vb) << 16);
            }
            uint4 q;
            q.x = parts[0]; q.y = parts[1]; q.z = parts[2]; q.w = parts[3];
            *(uint4*)(dst + (size_t)w * 64 + slot * 8) = q;   // coalesced 16B/lane
        }
        __syncthreads();   // lf safe to overwrite next iteration
    }
}

// ---- kernel 3 (fast path): persistent-block conv via implicit GEMM ----
// v6 = v4's proven inner loop (48KB LDS, XCD locality, swapped MFMA, float4
// stores) wrapped in a persistent-block unit loop: 768 blocks (3/CU), each
// handles 5-6 contiguous (n,h) units within its XCD's chunk of 504.
// Tests/attacks the ~50ns-per-workgroup front-end cost implied by r0-r3 data.
// Pipelining: next unit's DMA is issued before the current epilogue, so the
// 48KB load overlaps epilogue VALU + stores.
__global__ __launch_bounds__(256, 2)
void conv_mfma_v6(const u16* __restrict__ xq, const u16* __restrict__ wq,
                  const float* __restrict__ bias, const float* __restrict__ gamma,
                  const float* __restrict__ beta, const float* __restrict__ rmean,
                  const float* __restrict__ rvar, float* __restrict__ out) {
    __shared__ u16 in_lds[3 * 128 * 64];   // 48 KB, rows h0..h0+2, swizzled layout
    __shared__ float s_scale[CO], s_shift[CO], s_bias[CO];

    const int tid = threadIdx.x;
    // unit partition: XCD k = blockIdx&7 owns units [k*504, (k+1)*504);
    // its 96 blocks split 504 units: first 24 get 6, rest get 5 (contiguous).
    const int k = blockIdx.x & 7;
    const int l = blockIdx.x >> 3;
    const int lmin = (l < 24) ? l : 24;
    const int start = k * 504 + l * 5 + lmin;
    const int cnt   = 5 + (l < 24 ? 1 : 0);

    const int wv   = tid >> 6;
    const int lane = tid & 63;

    if (tid < CO) {
        float sc = gamma[tid] * rsqrtf(rvar[tid] + 1e-5f);
        s_scale[tid] = sc;
        s_shift[tid] = beta[tid] - rmean[tid] * sc;
        s_bias[tid]  = bias[tid];
    }

    auto issue_dma = [&](int u) {
        int n  = u / 126;
        int h0 = u - n * 126;
        const u16* src = xq + (size_t)(n * 128 + h0) * 8192;
#pragma unroll
        for (int s = 0; s < 12; ++s) {
            int chunk = s * 4 + wv;                      // 48 chunks of 512 u16 (1 KB)
            const u16* gp = src + chunk * 512 + lane * 8;
            u16*       lp = in_lds + chunk * 512 + lane * 8;
            __builtin_amdgcn_global_load_lds(
                (const __attribute__((address_space(1))) u32*)gp,
                (__attribute__((address_space(3))) u32*)lp, 16, 0, 0);
        }
    };

    const int li = tid & 15;          // lane & 15
    const int qd = (tid & 63) >> 4;   // quad
    const int wm = wv & 1;            // co-half
    const int wn = wv >> 1;           // pixel-half

    const uint4* wg = (const uint4*)wq;   // [tap][co][g] 16B granules
    const f32x4 zero4 = {0.f, 0.f, 0.f, 0.f};

    issue_dma(start);

    for (int t = 0; t < cnt; ++t) {
        const int u  = start + t;
        const int n  = u / 126;
        const int h0 = u - n * 126;

        __syncthreads();    // DMA(t) landed (barrier drains vmcnt); LDS ready

        f32x4 acc[4][4];
#pragma unroll
        for (int i = 0; i < 4; ++i)
#pragma unroll
            for (int j = 0; j < 4; ++j) acc[i][j] = zero4;

        // barrier-free K-loop: 9 taps x 2 K-steps of 32 (v4 verbatim)
#pragma unroll 1
        for (int kh = 0; kh < 3; ++kh) {
#pragma unroll
            for (int kw = 0; kw < 3; ++kw) {
                const int tap = kh * 3 + kw;
#pragma unroll
                for (int ks = 0; ks < 2; ++ks) {
                    short8 a[4], b[4];
#pragma unroll
                    for (int i = 0; i < 4; ++i) {
                        int co = wm * 64 + i * 16 + li;
                        a[i] = __builtin_bit_cast(short8,
                            wg[tap * 1024 + co * 8 + ks * 4 + qd]);   // weights (L1/L2)
                    }
#pragma unroll
                    for (int j = 0; j < 4; ++j) {
                        int w = wn * 64 + j * 16 + li + kw;           // input col
                        int g = ks * 4 + qd;                          // ci group
                        b[j] = *(const short8*)&in_lds[(size_t)(kh * 128 + w) * 64 +
                                                       ((g ^ (w & 7)) * 8)];
                    }
                    // SWAPPED operands: A=pixels, B=weights => D row=wo, col=co
#pragma unroll
                    for (int i = 0; i < 4; ++i)
#pragma unroll
                        for (int j = 0; j < 4; ++j)
                            acc[i][j] = __builtin_amdgcn_mfma_f32_16x16x32_bf16(
                                b[j], a[i], acc[i][j], 0, 0, 0);
                }
            }
        }

        __syncthreads();    // all waves done reading in_lds for unit t
        if (t + 1 < cnt) issue_dma(u + 1);   // overlap next DMA with epilogue

        // epilogue: bias + mish + BN affine; vectorized stores
        const bool al16 = ((h0 & 1) == 0);
        float* ob = out + (size_t)n * CO * (HO * WO) + (size_t)h0 * WO;
#pragma unroll
        for (int i = 0; i < 4; ++i) {
            int co = wm * 64 + i * 16 + li;
            float sc = s_scale[co], sh = s_shift[co], bs = s_bias[co];
            float* op = ob + (size_t)co * (HO * WO);
#pragma unroll
            for (int j = 0; j < 4; ++j) {
                int wo0 = wn * 64 + j * 16 + qd * 4;
                f32x4 v;
#pragma unroll
                for (int r = 0; r < 4; ++r) {
                    float z  = acc[i][j][r] + bs;
                    float u1 = 1.0f + __expf(fminf(z, 20.0f));
                    float u2 = u1 * u1;
                    float tt = __fdividef(u2 - 1.0f, u2 + 1.0f);  // tanh(softplus(z))
                    v[r] = z * tt * sc + sh;
                }
                if (wo0 + 3 < WO) {
                    if (al16) {
                        *(f32x4*)(op + wo0) = v;
                    } else {
                        float2 t0; t0.x = v[0]; t0.y = v[1];
                        float2 t1; t1.x = v[2]; t1.y = v[3];
                        *(float2*)(op + wo0)     = t0;
                        *(float2*)(op + wo0 + 2) = t1;
                    }
                } else {
#pragma unroll
                    for (int r = 0; r < 4; ++r)
                        if (wo0 + r < WO) op[wo0 + r] = v[r];
                }
            }
        }
    }
}

// ---- fallback (round-1) conv: used only if ws too small for xq ----
__global__ __launch_bounds__(256, 2)
void conv_mfma(const float* __restrict__ x, const u16* __restrict__ wq,
               const float* __restrict__ bias, const float* __restrict__ gamma,
               const float* __restrict__ beta, const float* __restrict__ rmean,
               const float* __restrict__ rvar, float* __restrict__ out) {
    __shared__ u32 in_lds[3 * 130 * 32];
    __shared__ float s_scale[CO], s_shift[CO], s_bias[CO];

    const int tid = threadIdx.x;
    const int h0  = blockIdx.x;
    const int n   = blockIdx.y;

    if (tid < CO) {
        float sc = gamma[tid] * rsqrtf(rvar[tid] + 1e-5f);
        s_scale[tid] = sc;
        s_shift[tid] = beta[tid] - rmean[tid] * sc;
        s_bias[tid]  = bias[tid];
    }
    if (tid < 48) {
        int kh  = tid >> 4;
        int rem = tid & 15;
        int w   = 128 + (rem & 1);
        int g   = rem >> 1;
        uint4 z = {0u, 0u, 0u, 0u};
        *(uint4*)&in_lds[(kh * 130 + w) * 32 + ((g ^ (w & 7)) * 4)] = z;
    }
    const float* xb = x + (size_t)n * CI * HH * WW;
    for (int it = 0; it < 12; ++it) {
        int idx = it * 256 + tid;
        int w   = idx & 127;
        int g   = (idx >> 7) & 7;
        int kh  = idx >> 10;
        const float* p = xb + (g * 8) * (HH * WW) + (h0 + kh) * WW + w;
        float v[8];
#pragma unroll
        for (int j = 0; j < 8; ++j) v[j] = p[j * (HH * WW)];
        uint4 q;
        q.x = (u32)f2bf(v[0]) | ((u32)f2bf(v[1]) << 16);
        q.y = (u32)f2bf(v[2]) | ((u32)f2bf(v[3]) << 16);
        q.z = (u32)f2bf(v[4]) | ((u32)f2bf(v[5]) << 16);
        q.w = (u32)f2bf(v[6]) | ((u32)f2bf(v[7]) << 16);
        *(uint4*)&in_lds[(kh * 130 + w) * 32 + ((g ^ (w & 7)) * 4)] = q;
    }
    __syncthreads();

    const int wv = tid >> 6;
    const int li = tid & 15;
    const int qd = (tid & 63) >> 4;
    const int wm = wv & 1;
    const int wn = wv >> 1;

    f32x4 zero4 = {0.f, 0.f, 0.f, 0.f};
    f32x4 acc[4][4];
#pragma unroll
    for (int i = 0; i < 4; ++i)
#pragma unroll
        for (int j = 0; j < 4; ++j) acc[i][j] = zero4;

    const uint4* wg = (const uint4*)wq;

#pragma unroll 1
    for (int kh = 0; kh < 3; ++kh) {
#pragma unroll
        for (int kw = 0; kw < 3; ++kw) {
            const int tap = kh * 3 + kw;
#pragma unroll
            for (int ks = 0; ks < 2; ++ks) {
                short8 a[4], b[4];
#pragma unroll
                for (int i = 0; i < 4; ++i) {
                    int co = wm * 64 + i * 16 + li;
                    a[i] = __builtin_bit_cast(short8,
                        wg[tap * 1024 + co * 8 + ks * 4 + qd]);
                }
#pragma unroll
                for (int j = 0; j < 4; ++j) {
                    int w = wn * 64 + j * 16 + li + kw;
                    int g = ks * 4 + qd;
                    b[j] = *(const short8*)&in_lds[(kh * 130 + w) * 32 +
                                                   ((g ^ (w & 7)) * 4)];
                }
#pragma unroll
                for (int i = 0; i < 4; ++i)
#pragma unroll
                    for (int j = 0; j < 4; ++j)
                        acc[i][j] = __builtin_amdgcn_mfma_f32_16x16x32_bf16(
                            a[i], b[j], acc[i][j], 0, 0, 0);
            }
        }
    }

    float* ob = out + (size_t)n * CO * (HO * WO) + (size_t)h0 * WO;
#pragma unroll
    for (int j = 0; j < 4; ++j) {
        int wo = wn * 64 + j * 16 + li;
        if (wo < WO) {
#pragma unroll
            for (int i = 0; i < 4; ++i) {
#pragma unroll
                for (int r = 0; r < 4; ++r) {
                    int co  = wm * 64 + i * 16 + qd * 4 + r;
                    float z  = acc[i][j][r] + s_bias[co];
                    float u  = 1.0f + __expf(fminf(z, 20.0f));
                    float u2 = u * u;
                    float t  = __fdividef(u2 - 1.0f, u2 + 1.0f);
                    ob[(size_t)co * (HO * WO) + wo] = z * t * s_scale[co] + s_shift[co];
                }
            }
        }
    }
}

extern "C" void kernel_launch(void* const* d_in, const int* in_sizes, int n_in,
                              void* d_out, int out_size, void* d_ws, size_t ws_size,
                              hipStream_t stream) {
    const float* x     = (const float*)d_in[0];
    const float* wt    = (const float*)d_in[1];
    const float* bias  = (const float*)d_in[2];
    const float* gamma = (const float*)d_in[3];
    const float* beta  = (const float*)d_in[4];
    const float* rmean = (const float*)d_in[5];
    const float* rvar  = (const float*)d_in[6];

    const size_t XQ_BYTES = (size_t)64 * 1024 * 1024;    // 32*128*128*64*2 = 64 MiB
    const size_t WQ_BYTES = (size_t)9 * CO * CI * 2;     // 144 KiB

    if (ws_size >= XQ_BYTES + WQ_BYTES) {
        u16* xq = (u16*)d_ws;
        u16* wq = (u16*)((char*)d_ws + XQ_BYTES);
        hipLaunchKernelGGL(reorder_w, dim3(72), dim3(256), 0, stream, wt, wq);
        hipLaunchKernelGGL(prep_x, dim3(512), dim3(256), 0, stream, x, xq);
        hipLaunchKernelGGL(conv_mfma_v6, dim3(768), dim3(256), 0, stream,
                           xq, wq, bias, gamma, beta, rmean, rvar, (float*)d_out);
    } else {
        u16* wq = (u16*)d_ws;
        hipLaunchKernelGGL(reorder_w, dim3(288), dim3(256), 0, stream, wt, wq);
        hipLaunchKernelGGL(conv_mfma, dim3(HO, 32), dim3(256), 0, stream,
                           x, wq, bias, gamma, beta, rmean, rvar, (float*)d_out);
    }
}

// Round 5
// 560.244 us; speedup vs baseline: 1.0447x; 1.0447x over previous
//
#include <hip/hip_runtime.h>

typedef unsigned int  u32;
typedef unsigned short u16;
typedef __attribute__((ext_vector_type(8))) short short8;
typedef __attribute__((ext_vector_type(4))) float f32x4;

#define CI 64
#define CO 128
#define HH 128
#define WW 128
#define HO 126
#define WO 126

// round-to-nearest-even fp32 -> bf16 (bits)
__device__ __forceinline__ u16 f2bf(float f) {
    u32 u = __builtin_bit_cast(u32, f);
    u = (u + 0x7FFFu + ((u >> 16) & 1u)) >> 16;
    return (u16)u;
}

// ---- kernel 1: reorder weights (C_out,C_in,3,3) fp32 -> [tap][co][ci] bf16 ----
__global__ void reorder_w(const float* __restrict__ w, u16* __restrict__ wq) {
    int i = blockIdx.x * 256 + threadIdx.x;     // 9*128*64 = 73728
    if (i < 9 * CO * CI) {
        int ci  = i & 63;
        int co  = (i >> 6) & 127;
        int tap = i >> 13;
        wq[i] = f2bf(w[(co * CI + ci) * 9 + tap]);
    }
}

// ---- kernel 2 (fast path): x fp32 NCHW -> bf16 swizzled-NHWC in ws ----
// Coalesced reads + LDS transpose (r2-proven version).
// Global layout out: xq[(n*128+h)*8192 + w*64 + slot*8 + j], ci = (slot^(w&7))*8 + j.
__global__ __launch_bounds__(256)
void prep_x(const float* __restrict__ x, u16* __restrict__ xq) {
    __shared__ float lf[64 * 128];         // 32 KB
    const int row = blockIdx.x;            // n*128 + h, 4096 rows
    const int n = row >> 7, h = row & 127;
    const float* xb = x + (size_t)n * CI * HH * WW + (size_t)h * WW;

    const int w4  = threadIdx.x & 31;      // float4 index along w
    const int ci0 = threadIdx.x >> 5;      // 0..7
#pragma unroll
    for (int it = 0; it < 8; ++it) {
        int ci = it * 8 + ci0;
        f32x4 v = *(const f32x4*)(xb + (size_t)ci * (HH * WW) + w4 * 4);  // coalesced
        int s = (ci >> 3) ^ (ci & 7);
        *(f32x4*)&lf[ci * 128 + ((w4 ^ s) * 4)] = v;
    }
    __syncthreads();

    u16* dst = xq + (size_t)row * 8192;
#pragma unroll
    for (int it = 0; it < 4; ++it) {
        int idx  = it * 256 + threadIdx.x; // 1024 = 128 w * 8 slots
        int slot = idx & 7;
        int w    = idx >> 3;
        int g    = slot ^ (w & 7);
        int wq4  = w >> 2, wr = w & 3;
        u32 parts[4];
#pragma unroll
        for (int jj = 0; jj < 4; ++jj) {
            int ca = g * 8 + 2 * jj;
            int cb = ca + 1;
            float va = lf[ca * 128 + ((wq4 ^ ((ca >> 3) ^ (ca & 7))) * 4) + wr];
            float vb = lf[cb * 128 + ((wq4 ^ ((cb >> 3) ^ (cb & 7))) * 4) + wr];
            parts[jj] = (u32)f2bf(va) | ((u32)f2bf(vb) << 16);
        }
        uint4 q;
        q.x = parts[0]; q.y = parts[1]; q.z = parts[2]; q.w = parts[3];
        *(uint4*)(dst + (size_t)w * 64 + slot * 8) = q;   // coalesced 16B/lane
    }
}

// ---- kernel 3 (fast path): conv via implicit GEMM, half-row tiles ----
// v7 = v4 inner loop resized for occupancy: block = 128co x 64wo, stages
// 3 rows x 72 w = 27 KB LDS -> 5 blocks/CU (20 waves/CU, was ~10).
// Each wave owns a co-quarter: acc[2][4] (32 VGPRs). launch_bounds(256,5)
// caps VGPR at ~102 (est. use ~80). 8064 blocks, bijective XCD chunking
// (1008 h-contiguous units per XCD) keeps the r2 FETCH/L2 win.
__global__ __launch_bounds__(256, 5)
void conv_mfma_v7(const u16* __restrict__ xq, const u16* __restrict__ wq,
                  const float* __restrict__ bias, const float* __restrict__ gamma,
                  const float* __restrict__ beta, const float* __restrict__ rmean,
                  const float* __restrict__ rvar, float* __restrict__ out) {
    __shared__ u16 in_lds[3 * 72 * 64];    // 27648 B, rows h0..h0+2, w in [ws0, ws0+72)
    __shared__ float s_scale[CO], s_shift[CO], s_bias[CO];

    const int tid = threadIdx.x;
    // bijective XCD swizzle over 8064 = 8 * 1008 blocks
    const int D = blockIdx.x;
    const int L = (D & 7) * 1008 + (D >> 3);
    const int g  = L / 126;              // 0..63 = (n, half)
    const int h0 = L - g * 126;          // 0..125
    const int n    = g >> 1;
    const int half = g & 1;
    const int W0   = half * 64;          // output wo base
    const int ws0  = half * 56;          // staged w base (56..127 covers w<=127)
    const int woff = half * 8;           // W0 - ws0

    const int wv   = tid >> 6;
    const int lane = tid & 63;

    // DMA rows h0..h0+2, 72 w each: 27 chunks of 1 KB (9 per row)
    const u16* src = xq + (size_t)(n * 128 + h0) * 8192 + ws0 * 64;
#pragma unroll
    for (int s = 0; s < 7; ++s) {
        int c = s * 4 + wv;
        if (c < 27) {
            int r  = (c >= 18) ? 2 : ((c >= 9) ? 1 : 0);
            int cr = c - r * 9;
            const u16* gp = src + (size_t)r * 8192 + cr * 512 + lane * 8;
            u16*       lp = in_lds + r * 4608 + cr * 512 + lane * 8;
            __builtin_amdgcn_global_load_lds(
                (const __attribute__((address_space(1))) u32*)gp,
                (__attribute__((address_space(3))) u32*)lp, 16, 0, 0);
        }
    }

    if (tid < CO) {                                  // overlaps DMA latency
        float sc = gamma[tid] * rsqrtf(rvar[tid] + 1e-5f);
        s_scale[tid] = sc;
        s_shift[tid] = beta[tid] - rmean[tid] * sc;
        s_bias[tid]  = bias[tid];
    }
    __syncthreads();

    const int li = tid & 15;          // lane & 15
    const int qd = (tid & 63) >> 4;   // quad

    f32x4 zero4 = {0.f, 0.f, 0.f, 0.f};
    f32x4 acc[2][4];
#pragma unroll
    for (int i = 0; i < 2; ++i)
#pragma unroll
        for (int j = 0; j < 4; ++j) acc[i][j] = zero4;

    // weight granule base: wg[tap*1024 + co*8 + ks*4 + qd], co = wv*32 + i*16 + li
    const uint4* wp = (const uint4*)wq + ((wv * 32 + li) * 8 + qd);

    // barrier-free K-loop: 9 taps x 2 K-steps of 32 (v4 structure, resized)
#pragma unroll 1
    for (int kh = 0; kh < 3; ++kh) {
#pragma unroll
        for (int kw = 0; kw < 3; ++kw) {
            const int tap = kh * 3 + kw;
#pragma unroll
            for (int ks = 0; ks < 2; ++ks) {
                short8 a[2], b[4];
#pragma unroll
                for (int i = 0; i < 2; ++i)
                    a[i] = __builtin_bit_cast(short8,
                        wp[tap * 1024 + i * 128 + ks * 4]);   // weights (L1/L2)
#pragma unroll
                for (int j = 0; j < 4; ++j) {
                    int wl = woff + j * 16 + li + kw;         // local w (ws0-relative)
                    int gg = ks * 4 + qd;                     // ci group
                    // (w & 7) == (wl & 7) since ws0 is 0 or 56 (both ≡ 0 mod 8)
                    b[j] = *(const short8*)&in_lds[(kh * 72 + wl) * 64 +
                                                   ((gg ^ (wl & 7)) * 8)];
                }
                // SWAPPED operands: A=pixels, B=weights => D row=wo, col=co
#pragma unroll
                for (int i = 0; i < 2; ++i)
#pragma unroll
                    for (int j = 0; j < 4; ++j)
                        acc[i][j] = __builtin_amdgcn_mfma_f32_16x16x32_bf16(
                            b[j], a[i], acc[i][j], 0, 0, 0);
            }
        }
    }

    // epilogue: bias + mish + BN affine; vectorized stores (lane owns 4 wo of 1 co)
    const bool al16 = ((h0 & 1) == 0);   // (h0*126 + W0) % 4 == 0 iff h0 even
    float* ob = out + (size_t)n * CO * (HO * WO) + (size_t)h0 * WO + W0;
#pragma unroll
    for (int i = 0; i < 2; ++i) {
        int co = wv * 32 + i * 16 + li;
        float sc = s_scale[co], sh = s_shift[co], bs = s_bias[co];
        float* op = ob + (size_t)co * (HO * WO);
#pragma unroll
        for (int j = 0; j < 4; ++j) {
            int lo  = j * 16 + qd * 4;       // store offset within the 64-wo tile
            int wo0 = W0 + lo;               // global wo of v[0]
            f32x4 v;
#pragma unroll
            for (int r = 0; r < 4; ++r) {
                float z  = acc[i][j][r] + bs;
                float u  = 1.0f + __expf(fminf(z, 20.0f));
                float u2 = u * u;
                float t  = __fdividef(u2 - 1.0f, u2 + 1.0f);  // tanh(softplus(z))
                v[r] = z * t * sc + sh;
            }
            if (wo0 + 3 < WO) {
                if (al16) {
                    *(f32x4*)(op + lo) = v;
                } else {
                    float2 t0; t0.x = v[0]; t0.y = v[1];
                    float2 t1; t1.x = v[2]; t1.y = v[3];
                    *(float2*)(op + lo)     = t0;
                    *(float2*)(op + lo + 2) = t1;
                }
            } else {
#pragma unroll
                for (int r = 0; r < 4; ++r)
                    if (wo0 + r < WO) op[lo + r] = v[r];
            }
        }
    }
}

// ---- fallback (round-1) conv: used only if ws too small for xq ----
__global__ __launch_bounds__(256, 2)
void conv_mfma(const float* __restrict__ x, const u16* __restrict__ wq,
               const float* __restrict__ bias, const float* __restrict__ gamma,
               const float* __restrict__ beta, const float* __restrict__ rmean,
               const float* __restrict__ rvar, float* __restrict__ out) {
    __shared__ u32 in_lds[3 * 130 * 32];
    __shared__ float s_scale[CO], s_shift[CO], s_bias[CO];

    const int tid = threadIdx.x;
    const int h0  = blockIdx.x;
    const int n   = blockIdx.y;

    if (tid < CO) {
        float sc = gamma[tid] * rsqrtf(rvar[tid] + 1e-5f);
        s_scale[tid] = sc;
        s_shift[tid] = beta[tid] - rmean[tid] * sc;
        s_bias[tid]  = bias[tid];
    }
    if (tid < 48) {
        int kh  = tid >> 4;
        int rem = tid & 15;
        int w   = 128 + (rem & 1);
        int g   = rem >> 1;
        uint4 z = {0u, 0u, 0u, 0u};
        *(uint4*)&in_lds[(kh * 130 + w) * 32 + ((g ^ (w & 7)) * 4)] = z;
    }
    const float* xb = x + (size_t)n * CI * HH * WW;
    for (int it = 0; it < 12; ++it) {
        int idx = it * 256 + tid;
        int w   = idx & 127;
        int g   = (idx >> 7) & 7;
        int kh  = idx >> 10;
        const float* p = xb + (g * 8) * (HH * WW) + (h0 + kh) * WW + w;
        float v[8];
#pragma unroll
        for (int j = 0; j < 8; ++j) v[j] = p[j * (HH * WW)];
        uint4 q;
        q.x = (u32)f2bf(v[0]) | ((u32)f2bf(v[1]) << 16);
        q.y = (u32)f2bf(v[2]) | ((u32)f2bf(v[3]) << 16);
        q.z = (u32)f2bf(v[4]) | ((u32)f2bf(v[5]) << 16);
        q.w = (u32)f2bf(v[6]) | ((u32)f2bf(v[7]) << 16);
        *(uint4*)&in_lds[(kh * 130 + w) * 32 + ((g ^ (w & 7)) * 4)] = q;
    }
    __syncthreads();

    const int wv = tid >> 6;
    const int li = tid & 15;
    const int qd = (tid & 63) >> 4;
    const int wm = wv & 1;
    const int wn = wv >> 1;

    f32x4 zero4 = {0.f, 0.f, 0.f, 0.f};
    f32x4 acc[4][4];
#pragma unroll
    for (int i = 0; i < 4; ++i)
#pragma unroll
        for (int j = 0; j < 4; ++j) acc[i][j] = zero4;

    const uint4* wg = (const uint4*)wq;

#pragma unroll 1
    for (int kh = 0; kh < 3; ++kh) {
#pragma unroll
        for (int kw = 0; kw < 3; ++kw) {
            const int tap = kh * 3 + kw;
#pragma unroll
            for (int ks = 0; ks < 2; ++ks) {
                short8 a[4], b[4];
#pragma unroll
                for (int i = 0; i < 4; ++i) {
                    int co = wm * 64 + i * 16 + li;
                    a[i] = __builtin_bit_cast(short8,
                        wg[tap * 1024 + co * 8 + ks * 4 + qd]);
                }
#pragma unroll
                for (int j = 0; j < 4; ++j) {
                    int w = wn * 64 + j * 16 + li + kw;
                    int g = ks * 4 + qd;
                    b[j] = *(const short8*)&in_lds[(kh * 130 + w) * 32 +
                                                   ((g ^ (w & 7)) * 4)];
                }
#pragma unroll
                for (int i = 0; i < 4; ++i)
#pragma unroll
                    for (int j = 0; j < 4; ++j)
                        acc[i][j] = __builtin_amdgcn_mfma_f32_16x16x32_bf16(
                            a[i], b[j], acc[i][j], 0, 0, 0);
            }
        }
    }

    float* ob = out + (size_t)n * CO * (HO * WO) + (size_t)h0 * WO;
#pragma unroll
    for (int j = 0; j < 4; ++j) {
        int wo = wn * 64 + j * 16 + li;
        if (wo < WO) {
#pragma unroll
            for (int i = 0; i < 4; ++i) {
#pragma unroll
                for (int r = 0; r < 4; ++r) {
                    int co  = wm * 64 + i * 16 + qd * 4 + r;
                    float z  = acc[i][j][r] + s_bias[co];
                    float u  = 1.0f + __expf(fminf(z, 20.0f));
                    float u2 = u * u;
                    float t  = __fdividef(u2 - 1.0f, u2 + 1.0f);
                    ob[(size_t)co * (HO * WO) + wo] = z * t * s_scale[co] + s_shift[co];
                }
            }
        }
    }
}

extern "C" void kernel_launch(void* const* d_in, const int* in_sizes, int n_in,
                              void* d_out, int out_size, void* d_ws, size_t ws_size,
                              hipStream_t stream) {
    const float* x     = (const float*)d_in[0];
    const float* wt    = (const float*)d_in[1];
    const float* bias  = (const float*)d_in[2];
    const float* gamma = (const float*)d_in[3];
    const float* beta  = (const float*)d_in[4];
    const float* rmean = (const float*)d_in[5];
    const float* rvar  = (const float*)d_in[6];

    const size_t XQ_BYTES = (size_t)64 * 1024 * 1024;    // 32*128*128*64*2 = 64 MiB
    const size_t WQ_BYTES = (size_t)9 * CO * CI * 2;     // 144 KiB

    if (ws_size >= XQ_BYTES + WQ_BYTES) {
        u16* xq = (u16*)d_ws;
        u16* wq = (u16*)((char*)d_ws + XQ_BYTES);
        hipLaunchKernelGGL(reorder_w, dim3(288), dim3(256), 0, stream, wt, wq);
        hipLaunchKernelGGL(prep_x, dim3(4096), dim3(256), 0, stream, x, xq);
        hipLaunchKernelGGL(conv_mfma_v7, dim3(8064), dim3(256), 0, stream,
                           xq, wq, bias, gamma, beta, rmean, rvar, (float*)d_out);
    } else {
        u16* wq = (u16*)d_ws;
        hipLaunchKernelGGL(reorder_w, dim3(288), dim3(256), 0, stream, wt, wq);
        hipLaunchKernelGGL(conv_mfma, dim3(HO, 32), dim3(256), 0, stream,
                           x, wq, bias, gamma, beta, rmean, rvar, (float*)d_out);
    }
}